// Round 1
// baseline (48.740 us; speedup 1.0000x reference)
//
#include <hip/hip_runtime.h>

// out[b,c,y,x] = sum_{i,j} Dot[b,3i+j,y,x] * V[b,c,y+i-1,x+j-1]  (zero-padded)
// b=16, c=64, h=w=128, fp32. Memory-bound (~143.6 MB ideal @ ~6.3 TB/s -> ~23us).

#define HH 128
#define WW 128
#define CC 64
#define BB 16
#define KK 9

__global__ __launch_bounds__(256) void msa_conv2d_kernel(
    const float* __restrict__ Dot,
    const float* __restrict__ V,
    float* __restrict__ out)
{
    __shared__ float dotRow[KK][WW];   // 9*128*4 = 4608 B

    const int cg = blockIdx.x;   // channel group (8 channels), 0..7
    const int y  = blockIdx.y;   // 0..127
    const int b  = blockIdx.z;   // 0..15

    const int tid = threadIdx.x;

    // Stage Dot[b, 0..8, y, 0..127] into LDS (shared across all 64 channels).
    const float* dotBase = Dot + ((size_t)b * KK) * (HH * WW) + (size_t)y * WW;
    #pragma unroll
    for (int idx = tid; idx < KK * WW; idx += 256) {
        int k = idx >> 7;     // /128
        int x = idx & 127;
        dotRow[k][x] = dotBase[(size_t)k * (HH * WW) + x];
    }
    __syncthreads();

    const int tx = tid & 31;          // x-quad index: covers x0..x0+3
    const int tc = tid >> 5;          // channel within group, 0..7
    const int c  = cg * 8 + tc;
    const int x0 = tx * 4;

    const float* vBase = V + (((size_t)b * CC + c) * HH) * WW;

    float acc0 = 0.f, acc1 = 0.f, acc2 = 0.f, acc3 = 0.f;

    #pragma unroll
    for (int i = 0; i < 3; ++i) {
        const int ry = y + i - 1;
        if (ry < 0 || ry >= HH) continue;
        const float* vrow = vBase + (size_t)ry * WW;
        const float4 vm = *reinterpret_cast<const float4*>(vrow + x0);
        const float vl = (x0 > 0)       ? vrow[x0 - 1] : 0.f;
        const float vr = (x0 + 4 < WW)  ? vrow[x0 + 4] : 0.f;
        const float v[6] = {vl, vm.x, vm.y, vm.z, vm.w, vr};
        #pragma unroll
        for (int j = 0; j < 3; ++j) {
            const int k = i * 3 + j;
            const float4 d = *reinterpret_cast<const float4*>(&dotRow[k][x0]);
            acc0 += d.x * v[0 + j];
            acc1 += d.y * v[1 + j];
            acc2 += d.z * v[2 + j];
            acc3 += d.w * v[3 + j];
        }
    }

    float* orow = out + (((size_t)b * CC + c) * HH + y) * WW + x0;
    *reinterpret_cast<float4*>(orow) = make_float4(acc0, acc1, acc2, acc3);
}

extern "C" void kernel_launch(void* const* d_in, const int* in_sizes, int n_in,
                              void* d_out, int out_size, void* d_ws, size_t ws_size,
                              hipStream_t stream)
{
    const float* Dot = (const float*)d_in[0];  // (16, 9, 128, 128)
    const float* V   = (const float*)d_in[1];  // (16, 64, 128, 128)
    float* out       = (float*)d_out;          // (16, 64, 128, 128)

    dim3 grid(CC / 8, HH, BB);  // (8, 128, 16) = 16384 blocks
    msa_conv2d_kernel<<<grid, 256, 0, stream>>>(Dot, V, out);
}

// Round 2
// 45.764 us; speedup vs baseline: 1.0650x; 1.0650x over previous
//
#include <hip/hip_runtime.h>

// out[b,c,y,x] = sum_{i,j} Dot[b,3i+j,y,x] * V[b,c,y+i-1,x+j-1]  (zero-padded)
// b=16, c=64, h=w=128, fp32. Memory-bound: ~143.6 MB ideal @ 6.3 TB/s -> ~23 us.
// Round-1 issue: latency-bound (2.2 TB/s achieved, VALUBusy 15%). Fix: 8x work
// per thread (all 64 channels per block), halo via __shfl instead of scalar
// loads, Dot weights register-resident.

#define HH 128
#define WW 128
#define CC 64
#define KK 9

__global__ __launch_bounds__(256) void msa_conv2d_kernel(
    const float* __restrict__ Dot,
    const float* __restrict__ V,
    float* __restrict__ out)
{
    __shared__ float dotRow[KK][WW];   // 4608 B

    const int y   = blockIdx.x;   // 0..127
    const int b   = blockIdx.y;   // 0..15
    const int tid = threadIdx.x;

    // Stage Dot[b, 0..8, y, :] once per (b,y); reused by all 64 channels.
    const float* dotBase = Dot + ((size_t)b * KK) * (HH * WW) + (size_t)y * WW;
    for (int idx = tid; idx < KK * WW; idx += 256) {
        int k = idx >> 7;
        int x = idx & 127;
        dotRow[k][x] = dotBase[(size_t)k * (HH * WW) + x];
    }
    __syncthreads();

    const int tx = tid & 31;     // x-quad index
    const int tc = tid >> 5;     // 0..7
    const int x0 = tx * 4;

    // Hoist the 9 weight float4s for this x-quad into registers.
    float4 d[KK];
    #pragma unroll
    for (int k = 0; k < KK; ++k)
        d[k] = *reinterpret_cast<const float4*>(&dotRow[k][x0]);

    const float* vB = V   + ((size_t)b * CC) * (HH * WW);
    float*       oB = out + ((size_t)b * CC) * (HH * WW) + (size_t)y * WW;

    #pragma unroll
    for (int cc = 0; cc < 8; ++cc) {
        const int c = cc * 8 + tc;
        const float* vC = vB + (size_t)c * (HH * WW);

        float acc0 = 0.f, acc1 = 0.f, acc2 = 0.f, acc3 = 0.f;

        #pragma unroll
        for (int i = 0; i < 3; ++i) {
            const int ry = y + i - 1;
            if (ry < 0 || ry >= HH) continue;   // block-uniform branch

            const float4 vm = *reinterpret_cast<const float4*>(vC + (size_t)ry * WW + x0);
            float vl = __shfl_up(vm.w, 1, 32);   // vrow[x0-1] from lane tx-1
            if (tx == 0)  vl = 0.f;
            float vr = __shfl_down(vm.x, 1, 32); // vrow[x0+4] from lane tx+1
            if (tx == 31) vr = 0.f;

            const float4 d0 = d[i * 3 + 0];
            const float4 d1 = d[i * 3 + 1];
            const float4 d2 = d[i * 3 + 2];

            acc0 += d0.x * vl   + d1.x * vm.x + d2.x * vm.y;
            acc1 += d0.y * vm.x + d1.y * vm.y + d2.y * vm.z;
            acc2 += d0.z * vm.y + d1.z * vm.z + d2.z * vm.w;
            acc3 += d0.w * vm.z + d1.w * vm.w + d2.w * vr;
        }

        *reinterpret_cast<float4*>(oB + (size_t)c * (HH * WW) + x0) =
            make_float4(acc0, acc1, acc2, acc3);
    }
}

extern "C" void kernel_launch(void* const* d_in, const int* in_sizes, int n_in,
                              void* d_out, int out_size, void* d_ws, size_t ws_size,
                              hipStream_t stream)
{
    const float* Dot = (const float*)d_in[0];  // (16, 9, 128, 128)
    const float* V   = (const float*)d_in[1];  // (16, 64, 128, 128)
    float* out       = (float*)d_out;          // (16, 64, 128, 128)

    dim3 grid(HH, 16);  // (y, b) = 2048 blocks = 8 per CU
    msa_conv2d_kernel<<<grid, 256, 0, stream>>>(Dot, V, out);
}

// Round 3
// 29.944 us; speedup vs baseline: 1.6277x; 1.5283x over previous
//
#include <hip/hip_runtime.h>

// out[b,c,y,x] = sum_{i,j} Dot[b,3i+j,y,x] * V[b,c,y+i-1,x+j-1]  (zero-padded)
// b=16, c=64, h=w=128, fp32. Ideal traffic ~143 MB @ 6.3 TB/s -> ~23 us floor.
// Round-2 lesson: XCD = blockid%8 decides per-XCD L2 locality. Round 1 was
// accidentally XCD-optimal (grid.x = channel group); round 2 broke it (grid.x
// = y). Here: explicit swizzle so each XCD owns contiguous (b,ypair) chunk,
// plus y-strip of 2 for register-level row reuse (2 loads/output vs 3).

#define HH 128
#define WW 128
#define CC 64
#define KK 9

__device__ __forceinline__ void accum3(float4& o, float vl, const float4& vm, float vr,
                                       const float4& d0, const float4& d1, const float4& d2)
{
    o.x += d0.x * vl   + d1.x * vm.x + d2.x * vm.y;
    o.y += d0.y * vm.x + d1.y * vm.y + d2.y * vm.z;
    o.z += d0.z * vm.y + d1.z * vm.z + d2.z * vm.w;
    o.w += d0.w * vm.z + d1.w * vm.w + d2.w * vr;
}

__global__ __launch_bounds__(256) void msa_conv2d_kernel(
    const float* __restrict__ Dot,
    const float* __restrict__ V,
    float* __restrict__ out)
{
    __shared__ float dotRow[2][KK][WW];   // 9216 B

    // XCD-bijective swizzle: 1024 blocks, XCD = n%8 (round-robin dispatch).
    // Give XCD k the contiguous chunk L in [k*128, (k+1)*128) of (b,ypair).
    const int n   = blockIdx.x;
    const int L   = (n & 7) * 128 + (n >> 3);
    const int b   = L >> 6;        // 0..15
    const int yp  = L & 63;        // 0..63
    const int y0  = yp * 2;

    const int tid = threadIdx.x;

    // Stage Dot[b, 0..8, y0..y0+1, :] (each Dot row read exactly once globally).
    const float* dotBase = Dot + ((size_t)b * KK) * (HH * WW);
    for (int t = tid; t < 2 * KK * WW; t += 256) {
        const int yy  = t / (KK * WW);
        const int rem = t - yy * (KK * WW);
        const int k   = rem >> 7;
        const int x   = rem & 127;
        dotRow[yy][k][x] = dotBase[(size_t)k * (HH * WW) + (size_t)(y0 + yy) * WW + x];
    }
    __syncthreads();

    const int tx = tid & 31;     // x-quad
    const int tc = tid >> 5;     // channel sub-index 0..7
    const int x0 = tx * 4;

    // Hoist both rows' weights to registers: 18 float4 (~72 VGPR), reused 8x.
    float4 dA[KK], dB[KK];
    #pragma unroll
    for (int k = 0; k < KK; ++k) {
        dA[k] = *reinterpret_cast<const float4*>(&dotRow[0][k][x0]);
        dB[k] = *reinterpret_cast<const float4*>(&dotRow[1][k][x0]);
    }

    const bool topOK = (y0 > 0);
    const bool botOK = (y0 + 2 < HH);
    const float4 z4 = make_float4(0.f, 0.f, 0.f, 0.f);

    const float* vB = V   + ((size_t)b * CC) * (HH * WW);
    float*       oB = out + ((size_t)b * CC) * (HH * WW);

    #pragma unroll
    for (int cc = 0; cc < 8; ++cc) {
        const int c = cc * 8 + tc;
        const float* vC = vB + (size_t)c * (HH * WW) + x0;

        // 4 independent loads in flight per channel.
        const float4 r0 = topOK ? *reinterpret_cast<const float4*>(vC + (size_t)(y0 - 1) * WW) : z4;
        const float4 r1 =         *reinterpret_cast<const float4*>(vC + (size_t)(y0    ) * WW);
        const float4 r2 =         *reinterpret_cast<const float4*>(vC + (size_t)(y0 + 1) * WW);
        const float4 r3 = botOK ? *reinterpret_cast<const float4*>(vC + (size_t)(y0 + 2) * WW) : z4;

        // Halos via cross-lane shuffle (width 32 keeps it within one channel).
        float l0 = __shfl_up(r0.w, 1, 32), h0 = __shfl_down(r0.x, 1, 32);
        float l1 = __shfl_up(r1.w, 1, 32), h1 = __shfl_down(r1.x, 1, 32);
        float l2 = __shfl_up(r2.w, 1, 32), h2 = __shfl_down(r2.x, 1, 32);
        float l3 = __shfl_up(r3.w, 1, 32), h3 = __shfl_down(r3.x, 1, 32);
        if (tx == 0)  { l0 = l1 = l2 = l3 = 0.f; }
        if (tx == 31) { h0 = h1 = h2 = h3 = 0.f; }

        float4 o0 = z4, o1 = z4;
        accum3(o0, l0, r0, h0, dA[0], dA[1], dA[2]);
        accum3(o0, l1, r1, h1, dA[3], dA[4], dA[5]);
        accum3(o0, l2, r2, h2, dA[6], dA[7], dA[8]);
        accum3(o1, l1, r1, h1, dB[0], dB[1], dB[2]);
        accum3(o1, l2, r2, h2, dB[3], dB[4], dB[5]);
        accum3(o1, l3, r3, h3, dB[6], dB[7], dB[8]);

        float* oC = oB + (size_t)c * (HH * WW) + x0;
        *reinterpret_cast<float4*>(oC + (size_t)(y0    ) * WW) = o0;
        *reinterpret_cast<float4*>(oC + (size_t)(y0 + 1) * WW) = o1;
    }
}

extern "C" void kernel_launch(void* const* d_in, const int* in_sizes, int n_in,
                              void* d_out, int out_size, void* d_ws, size_t ws_size,
                              hipStream_t stream)
{
    const float* Dot = (const float*)d_in[0];  // (16, 9, 128, 128)
    const float* V   = (const float*)d_in[1];  // (16, 64, 128, 128)
    float* out       = (float*)d_out;          // (16, 64, 128, 128)

    msa_conv2d_kernel<<<dim3(16 * 64), 256, 0, stream>>>(Dot, V, out);
}